// Round 4
// baseline (361.892 us; speedup 1.0000x reference)
//
#include <hip/hip_runtime.h>

#define GSZ  16
#define NVOX 4096        // 16^3
#define BB   4
#define DD   128
#define TPB1 256         // pass1 / compact block size
#define TILE 2048        // points per pass1/compact block
#define PPT  8           // points per thread (pass1/compact)

// ---------------------------------------------------------------------------
// Pass 1: voxel idx per point, packed (ptidx<<12)|idx into u32 (0xFFFFFFFF =
// masked), histogram counts, per-tile unmasked count.
// ---------------------------------------------------------------------------
__global__ __launch_bounds__(TPB1) void k_voxidx(const float* __restrict__ xyz,
                                                 const int* __restrict__ mask,
                                                 unsigned int* __restrict__ pack,
                                                 int* __restrict__ counts,
                                                 int* __restrict__ bcount,
                                                 int N, int NB) {
    int tile = blockIdx.x, b = blockIdx.y;
    __shared__ int s_cnt;
    if (threadIdx.x == 0) s_cnt = 0;
    __syncthreads();

    const float*  xb = xyz  + (size_t)b * N * 3;
    const int*    mb = mask + (size_t)b * N;
    unsigned int* pb = pack + (size_t)b * N;
    int*          cb = counts + b * NVOX;

    int p0 = tile * TILE + (int)threadIdx.x * PPT;
    int cnt = 0;

    if (p0 + PPT <= N) {
        float a[3 * PPT];
        float4* av = (float4*)a;
        const float4* xv = (const float4*)(xb + 3 * (size_t)p0);
#pragma unroll
        for (int q = 0; q < 6; q++) av[q] = xv[q];
        const int4* mv = (const int4*)(mb + p0);
        int4 mA = mv[0], mB = mv[1];
        int mk[PPT] = {mA.x, mA.y, mA.z, mA.w, mB.x, mB.y, mB.z, mB.w};
        unsigned int pk[PPT];
#pragma unroll
        for (int k = 0; k < PPT; k++) {
            int vx = min(max((int)(a[3 * k + 0] * (float)GSZ), 0), GSZ - 1);
            int vy = min(max((int)(a[3 * k + 1] * (float)GSZ), 0), GSZ - 1);
            int vz = min(max((int)(a[3 * k + 2] * (float)GSZ), 0), GSZ - 1);
            int idx = vz * GSZ * GSZ + vy * GSZ + vx;
            if (mk[k] != 0) {
                pk[k] = ((unsigned int)(p0 + k) << 12) | (unsigned int)idx;
                cnt++;
                atomicAdd(&cb[idx], 1);
            } else {
                pk[k] = 0xFFFFFFFFu;
            }
        }
        uint4* pv = (uint4*)(pb + p0);
        pv[0] = make_uint4(pk[0], pk[1], pk[2], pk[3]);
        pv[1] = make_uint4(pk[4], pk[5], pk[6], pk[7]);
    } else {
        for (int k = 0; k < PPT; k++) {
            int p = p0 + k;
            if (p >= N) break;
            float x = xb[3 * (size_t)p + 0];
            float y = xb[3 * (size_t)p + 1];
            float z = xb[3 * (size_t)p + 2];
            int vx = min(max((int)(x * (float)GSZ), 0), GSZ - 1);
            int vy = min(max((int)(y * (float)GSZ), 0), GSZ - 1);
            int vz = min(max((int)(z * (float)GSZ), 0), GSZ - 1);
            int idx = vz * GSZ * GSZ + vy * GSZ + vx;
            if (mb[p] != 0) {
                pb[p] = ((unsigned int)p << 12) | (unsigned int)idx;
                cnt++;
                atomicAdd(&cb[idx], 1);
            } else {
                pb[p] = 0xFFFFFFFFu;
            }
        }
    }
    atomicAdd(&s_cnt, cnt);
    __syncthreads();
    if (threadIdx.x == 0) bcount[b * NB + tile] = s_cnt;
}

// ---------------------------------------------------------------------------
// Pass 2: tiny exclusive scan of per-tile counts (one block)
// ---------------------------------------------------------------------------
__global__ void k_scan(const int* __restrict__ bcount, int* __restrict__ boff,
                       int* __restrict__ M, int NB) {
    int b = threadIdx.x;
    if (b < BB) {
        int run = 0;
        for (int j = 0; j < NB; j++) {
            boff[b * NB + j] = run;
            run += bcount[b * NB + j];
        }
        M[b] = run;
    }
}

// ---------------------------------------------------------------------------
// Pass 3: order-preserving compaction of packed entries
// ---------------------------------------------------------------------------
__global__ __launch_bounds__(TPB1) void k_compact(const unsigned int* __restrict__ pack,
                                                  const int* __restrict__ boff,
                                                  unsigned int* __restrict__ comp,
                                                  int N, int NB) {
    int tile = blockIdx.x, b = blockIdx.y;
    const unsigned int* pb = pack + (size_t)b * N;
    unsigned int*       ob = comp + (size_t)b * N;

    int p0 = tile * TILE + (int)threadIdx.x * PPT;
    unsigned int pk[PPT];
#pragma unroll
    for (int k = 0; k < PPT; k++) pk[k] = 0xFFFFFFFFu;

    if (p0 + PPT <= N) {
        const uint4* pv = (const uint4*)(pb + p0);
        uint4 A = pv[0], Bq = pv[1];
        pk[0] = A.x;  pk[1] = A.y;  pk[2] = A.z;  pk[3] = A.w;
        pk[4] = Bq.x; pk[5] = Bq.y; pk[6] = Bq.z; pk[7] = Bq.w;
    } else {
        for (int k = 0; k < PPT; k++)
            if (p0 + k < N) pk[k] = pb[p0 + k];
    }
    int cnt = 0;
#pragma unroll
    for (int k = 0; k < PPT; k++) cnt += (pk[k] != 0xFFFFFFFFu) ? 1 : 0;

    __shared__ int s[TPB1];
    s[threadIdx.x] = cnt;
    __syncthreads();
    for (int off = 1; off < TPB1; off <<= 1) {
        int v = (threadIdx.x >= (unsigned)off) ? s[threadIdx.x - off] : 0;
        __syncthreads();
        s[threadIdx.x] += v;
        __syncthreads();
    }
    int pos = boff[b * NB + tile] + s[threadIdx.x] - cnt;
#pragma unroll
    for (int k = 0; k < PPT; k++) {
        if (pk[k] != 0xFFFFFFFFu) ob[pos++] = pk[k];
    }
}

// ---------------------------------------------------------------------------
// Pass 4: scatter. Block owns one (b,d) row; compacted entries -> all-lane
// ds_add_f32 (no exec-mask dance, half the atomic instructions). Flush =
// coalesced stores with fused count-divide.
// ---------------------------------------------------------------------------
__global__ __launch_bounds__(1024, 8) void k_scatter(const float* __restrict__ feats,
                                                     const unsigned int* __restrict__ comp,
                                                     const int* __restrict__ M,
                                                     const int* __restrict__ counts,
                                                     float* __restrict__ out, int N) {
    __shared__ float acc[NVOX];
    int d = blockIdx.x & (DD - 1);
    int b = blockIdx.x >> 7;   // DD == 128

    for (int j = threadIdx.x; j < NVOX; j += 1024) acc[j] = 0.f;
    __syncthreads();

    int Mb = M[b];
    const float*        f  = feats + ((size_t)b * DD + (size_t)d) * (size_t)N;
    const unsigned int* cp = comp + (size_t)b * N;

    const int stride = 1024 * 4;
    int niter = Mb / stride;
    int nmain = niter * stride;
    int t4 = (int)threadIdx.x * 4;

    if (niter > 0) {
        uint4 e = *reinterpret_cast<const uint4*>(cp + t4);
        for (int it = 0; it < niter; it++) {
            int inext = (it + 1 < niter) ? (it + 1) * stride + t4 : t4;
            uint4 en = *reinterpret_cast<const uint4*>(cp + inext);
            float v0 = f[e.x >> 12];
            float v1 = f[e.y >> 12];
            float v2 = f[e.z >> 12];
            float v3 = f[e.w >> 12];
            atomicAdd(&acc[e.x & 0xFFFu], v0);
            atomicAdd(&acc[e.y & 0xFFFu], v1);
            atomicAdd(&acc[e.z & 0xFFFu], v2);
            atomicAdd(&acc[e.w & 0xFFFu], v3);
            e = en;
        }
    }
    for (int p = nmain + (int)threadIdx.x; p < Mb; p += 1024) {
        unsigned int ee = cp[p];
        atomicAdd(&acc[ee & 0xFFFu], f[ee >> 12]);
    }
    __syncthreads();

    const int* cb = counts + b * NVOX;
    float*     ob = out + ((size_t)b * DD + (size_t)d) * (size_t)NVOX;
    {
        int j = threadIdx.x;                       // NVOX/4 == 1024
        float4 a = reinterpret_cast<float4*>(acc)[j];
        int4   c = reinterpret_cast<const int4*>(cb)[j];
        a.x /= (float)max(c.x, 1);
        a.y /= (float)max(c.y, 1);
        a.z /= (float)max(c.z, 1);
        a.w /= (float)max(c.w, 1);
        reinterpret_cast<float4*>(ob)[j] = a;
    }
}

extern "C" void kernel_launch(void* const* d_in, const int* in_sizes, int n_in,
                              void* d_out, int out_size, void* d_ws, size_t ws_size,
                              hipStream_t stream) {
    const float* feats = (const float*)d_in[0];          // [B, D, N]
    const float* xyz   = (const float*)d_in[1];          // [B, N, 3]
    const int*   mask  = (const int*)d_in[2];            // [B, N]
    float*       out   = (float*)d_out;                  // [B, D, V]

    int N  = in_sizes[2] / BB;                           // mask is B*N
    int NB = (N + TILE - 1) / TILE;

    // workspace carve (all 16B-aligned)
    char* w = (char*)d_ws;
    int*          counts = (int*)w;                       w += (size_t)BB * NVOX * sizeof(int);   // 64 KB
    int*          bcount = (int*)w;                       w += ((size_t)BB * NB * sizeof(int) + 255) & ~255ull;
    int*          boff   = (int*)w;                       w += ((size_t)BB * NB * sizeof(int) + 255) & ~255ull;
    int*          Mcnt   = (int*)w;                       w += 256;
    unsigned int* pack   = (unsigned int*)w;              w += (size_t)BB * N * sizeof(unsigned int);
    unsigned int* comp   = (unsigned int*)w;

    // counts is accumulated -> must start at zero (ws poisoned each call)
    hipMemsetAsync(counts, 0, (size_t)BB * NVOX * sizeof(int), stream);

    k_voxidx <<<dim3(NB, BB), TPB1, 0, stream>>>(xyz, mask, pack, counts, bcount, N, NB);
    k_scan   <<<1, 64, 0, stream>>>(bcount, boff, Mcnt, NB);
    k_compact<<<dim3(NB, BB), TPB1, 0, stream>>>(pack, boff, comp, N, NB);
    k_scatter<<<BB * DD, 1024, 0, stream>>>(feats, comp, Mcnt, counts, out, N);
}

// Round 6
// 300.283 us; speedup vs baseline: 1.2052x; 1.2052x over previous
//
#include <hip/hip_runtime.h>

#define GSZ   16
#define NVOX  4096        // 16^3
#define BB    4
#define DD    128
#define PThr  256         // prep threads
#define PPT   16          // points per prep thread
#define PTILE (PThr * PPT) // 4096 points per prep tile

typedef __fp16 half2v __attribute__((ext_vector_type(2)));

// packed f16 LDS atomic add: adds (va,vb) to the half2 at LDS byte offset.
// LDS byte offset = low 32 bits of the generic address (shared aperture is
// 4GB-aligned, so low32 == offset).
__device__ __forceinline__ void lds_pk_add_f16(unsigned byte_off, float va, float vb) {
    half2v h = __builtin_amdgcn_cvt_pkrtz(va, vb);
    unsigned hv;
    __builtin_memcpy(&hv, &h, 4);
    asm volatile("ds_pk_add_f16 %0, %1" : : "v"(byte_off), "v"(hv) : "memory");
}

// ---------------------------------------------------------------------------
// Dispatch 1: voxel idx per point (u16, 0xFFFF = masked) + per-tile u16
// histograms written with plain stores (no global zero-init needed anywhere).
// ---------------------------------------------------------------------------
__global__ __launch_bounds__(PThr) void k_prep(const float* __restrict__ xyz,
                                               const int* __restrict__ mask,
                                               unsigned short* __restrict__ idxm,
                                               unsigned short* __restrict__ histg,
                                               int N, int NT) {
    __shared__ unsigned int hist[NVOX];
    const int tile = blockIdx.x, b = blockIdx.y;
    for (int j = threadIdx.x; j < NVOX; j += PThr) hist[j] = 0u;
    __syncthreads();

    const float*    xb = xyz  + (size_t)b * N * 3;
    const int*      mb = mask + (size_t)b * N;
    unsigned short* ib = idxm + (size_t)b * N;

    const int p0 = tile * PTILE + (int)threadIdx.x * PPT;

    if (p0 + PPT <= N) {
        float a[3 * PPT];
        float4* av = (float4*)a;
        const float4* xv = (const float4*)(xb + 3 * (size_t)p0);
#pragma unroll
        for (int q = 0; q < 12; q++) av[q] = xv[q];
        int mk[PPT];
        const int4* mv = (const int4*)(mb + p0);
#pragma unroll
        for (int q = 0; q < 4; q++) {
            int4 m4 = mv[q];
            mk[4*q+0] = m4.x; mk[4*q+1] = m4.y; mk[4*q+2] = m4.z; mk[4*q+3] = m4.w;
        }
        alignas(16) unsigned short pk[PPT];
#pragma unroll
        for (int k = 0; k < PPT; k++) {
            int vx = min(max((int)(a[3*k+0] * (float)GSZ), 0), GSZ - 1);
            int vy = min(max((int)(a[3*k+1] * (float)GSZ), 0), GSZ - 1);
            int vz = min(max((int)(a[3*k+2] * (float)GSZ), 0), GSZ - 1);
            int idx = vz * GSZ * GSZ + vy * GSZ + vx;
            if (mk[k] != 0) {
                pk[k] = (unsigned short)idx;
                atomicAdd(&hist[idx], 1u);
            } else {
                pk[k] = 0xFFFFu;
            }
        }
        uint4* dst = (uint4*)(ib + p0);
        dst[0] = ((const uint4*)pk)[0];
        dst[1] = ((const uint4*)pk)[1];
    } else {
        for (int k = 0; k < PPT; k++) {
            int p = p0 + k;
            if (p >= N) break;
            float x = xb[3*(size_t)p+0], y = xb[3*(size_t)p+1], z = xb[3*(size_t)p+2];
            int vx = min(max((int)(x * (float)GSZ), 0), GSZ - 1);
            int vy = min(max((int)(y * (float)GSZ), 0), GSZ - 1);
            int vz = min(max((int)(z * (float)GSZ), 0), GSZ - 1);
            int idx = vz * GSZ * GSZ + vy * GSZ + vx;
            if (mb[p] != 0) { ib[p] = (unsigned short)idx; atomicAdd(&hist[idx], 1u); }
            else            { ib[p] = 0xFFFFu; }
        }
    }
    __syncthreads();
    unsigned short* hg = histg + ((size_t)b * NT + tile) * NVOX;
    for (int j = threadIdx.x; j < NVOX; j += PThr) hg[j] = (unsigned short)hist[j];
}

// ---------------------------------------------------------------------------
// Dispatch 2: each block owns a (b, d-pair). half2 accumulator in LDS (16 KB);
// one ds_pk_add_f16 per (point, d-pair) -> half the LDS-atomic lane-ops.
// Counts derived per block by summing tile histograms (overlaps atomic drain).
// Flush = plain coalesced float4 stores with fused divide. No global atomics,
// no memsets anywhere.
// ---------------------------------------------------------------------------
__global__ __launch_bounds__(1024) void k_scatter(const float* __restrict__ feats,
                                                  const unsigned short* __restrict__ idxm,
                                                  const unsigned short* __restrict__ histg,
                                                  float* __restrict__ out, int N, int NT) {
    __shared__ half2v acc[NVOX];     // 16 KB: acc[v] = (sum_d0[v], sum_d1[v])
    const int dp = blockIdx.x & 63;  // DD/2 == 64
    const int b  = blockIdx.x >> 6;
    const int d0 = dp * 2;

    {
        half2v z = { (__fp16)0.f, (__fp16)0.f };
        for (int j = threadIdx.x; j < NVOX; j += 1024) acc[j] = z;
    }
    __syncthreads();

    const unsigned short* ib = idxm + (size_t)b * N;
    const float* f0 = feats + ((size_t)b * DD + (size_t)d0) * (size_t)N;
    const float* f1 = f0 + N;
    const unsigned accbase = (unsigned)(size_t)(void*)&acc[0];

#define PROC(idx_, va_, vb_)                                       \
    {                                                              \
        unsigned _i = (idx_);                                      \
        if (_i != 0xFFFFu) lds_pk_add_f16(accbase + _i * 4u, (va_), (vb_)); \
    }

    const int stride = 1024 * 8;
    const int niter  = N / stride;
    const int t8     = (int)threadIdx.x * 8;

    if (niter > 0) {
        uint4  iv = *(const uint4*)(ib + t8);
        float4 a0 = *(const float4*)(f0 + t8);
        float4 a1 = *(const float4*)(f0 + t8 + 4);
        float4 b0 = *(const float4*)(f1 + t8);
        float4 b1 = *(const float4*)(f1 + t8 + 4);
        for (int it = 0; it < niter; it++) {
            int inext = (it + 1 < niter) ? (it + 1) * stride + t8 : t8;
            uint4  ivn = *(const uint4*)(ib + inext);
            float4 a0n = *(const float4*)(f0 + inext);
            float4 a1n = *(const float4*)(f0 + inext + 4);
            float4 b0n = *(const float4*)(f1 + inext);
            float4 b1n = *(const float4*)(f1 + inext + 4);

            PROC(iv.x & 0xFFFFu, a0.x, b0.x)
            PROC(iv.x >> 16,     a0.y, b0.y)
            PROC(iv.y & 0xFFFFu, a0.z, b0.z)
            PROC(iv.y >> 16,     a0.w, b0.w)
            PROC(iv.z & 0xFFFFu, a1.x, b1.x)
            PROC(iv.z >> 16,     a1.y, b1.y)
            PROC(iv.w & 0xFFFFu, a1.z, b1.z)
            PROC(iv.w >> 16,     a1.w, b1.w)

            iv = ivn; a0 = a0n; a1 = a1n; b0 = b0n; b1 = b1n;
        }
    }
    for (int p = niter * stride + (int)threadIdx.x; p < N; p += 1024) {
        unsigned id = ib[p];
        if (id != 0xFFFFu) lds_pk_add_f16(accbase + id * 4u, f0[p], f1[p]);
    }
#undef PROC

    // sum per-voxel counts from tile histograms while LDS atomics drain
    const int v0 = (int)threadIdx.x * 4;        // 1024 * 4 == NVOX
    int c0 = 0, c1 = 0, c2 = 0, c3 = 0;
    {
        const unsigned short* hb = histg + (size_t)b * NT * NVOX + v0;
        for (int t = 0; t < NT; t++) {
            ushort4 h = *(const ushort4*)(hb + (size_t)t * NVOX);
            c0 += h.x; c1 += h.y; c2 += h.z; c3 += h.w;
        }
    }
    __syncthreads();

    half2v s0 = acc[v0+0], s1 = acc[v0+1], s2 = acc[v0+2], s3 = acc[v0+3];
    float i0 = 1.f / (float)max(c0, 1);
    float i1 = 1.f / (float)max(c1, 1);
    float i2 = 1.f / (float)max(c2, 1);
    float i3 = 1.f / (float)max(c3, 1);
    float4 oa, ob;
    oa.x = (float)s0.x * i0;  ob.x = (float)s0.y * i0;
    oa.y = (float)s1.x * i1;  ob.y = (float)s1.y * i1;
    oa.z = (float)s2.x * i2;  ob.z = (float)s2.y * i2;
    oa.w = (float)s3.x * i3;  ob.w = (float)s3.y * i3;
    float* r0 = out + ((size_t)b * DD + (size_t)d0) * (size_t)NVOX + v0;
    *(float4*)r0          = oa;
    *(float4*)(r0 + NVOX) = ob;
}

extern "C" void kernel_launch(void* const* d_in, const int* in_sizes, int n_in,
                              void* d_out, int out_size, void* d_ws, size_t ws_size,
                              hipStream_t stream) {
    const float* feats = (const float*)d_in[0];          // [B, D, N]
    const float* xyz   = (const float*)d_in[1];          // [B, N, 3]
    const int*   mask  = (const int*)d_in[2];            // [B, N]
    float*       out   = (float*)d_out;                  // [B, D, V]

    int N  = in_sizes[2] / BB;                           // mask is B*N
    int NT = (N + PTILE - 1) / PTILE;

    // workspace carve — everything fully overwritten each call, no memsets
    char* w = (char*)d_ws;
    unsigned short* idxm  = (unsigned short*)w;          // B*N u16 (~800 KB)
    w += (((size_t)BB * N * sizeof(unsigned short)) + 255) & ~(size_t)255;
    unsigned short* histg = (unsigned short*)w;          // B*NT*NVOX u16 (~800 KB)

    k_prep   <<<dim3(NT, BB), PThr, 0, stream>>>(xyz, mask, idxm, histg, N, NT);
    k_scatter<<<BB * (DD / 2), 1024, 0, stream>>>(feats, idxm, histg, out, N, NT);
}